// Round 18
// baseline (135.599 us; speedup 1.0000x reference)
//
#include <hip/hip_runtime.h>
#include <hip/hip_bf16.h>

typedef unsigned short u16;
typedef __attribute__((ext_vector_type(4))) int   int4v;
typedef __attribute__((ext_vector_type(4))) unsigned int uint4v;
typedef __attribute__((ext_vector_type(4))) unsigned short ushort4v;
typedef __attribute__((ext_vector_type(4))) float floatx4;
typedef __attribute__((ext_vector_type(8))) short bf16x8;
typedef _Float16 half8 __attribute__((ext_vector_type(8)));
typedef _Float16 half2v __attribute__((ext_vector_type(2)));

#define LRELU_NS 0.01f
#define SK 264   // LDS k-stride (u16 units): 256 + 8 pad, 16B-aligned rows

__device__ __forceinline__ float bitsToF(unsigned int b) {
    union { unsigned int u; float f; } v; v.u = b << 16; return v.f;
}
__device__ __forceinline__ u16 f2bf(float f) {
    __hip_bfloat16 h = __float2bfloat16(f);
    return *reinterpret_cast<u16*>(&h);
}
// 2-op leaky relu (f32): max(x, 0.01x) — exact for all finite x
__device__ __forceinline__ float lrelu(float v) {
    return fmaxf(v, LRELU_NS * v);
}
__device__ __forceinline__ u16 ldW(const void* p, int i, int isF32) {
    return isF32 ? f2bf(((const float*)p)[i]) : ((const u16*)p)[i];
}
__device__ __forceinline__ float ldF(const void* p, int i, int isF32) {
    return isF32 ? ((const float*)p)[i]
                 : bitsToF((unsigned int)((const u16*)p)[i]);
}
// float -> fp16 bits (native _Float16 cast = round-to-nearest-even)
__device__ __forceinline__ u16 f2h_bits(float f) {
    union { _Float16 h; u16 u; } v; v.h = (_Float16)f; return v.u;
}
// load -> fp16 bits (for the f16 pair path)
__device__ __forceinline__ u16 ldWh(const void* p, int i, int isF32) {
    float f = isF32 ? ((const float*)p)[i]
                    : bitsToF((unsigned int)((const u16*)p)[i]);
    return f2h_bits(f);
}
__device__ __forceinline__ half2v u2h2(unsigned int x) {
    union { unsigned int u; half2v h; } v; v.u = x; return v.h;
}
__device__ __forceinline__ unsigned int h22u(half2v x) {
    union { half2v h; unsigned int u; } v; v.h = x; return v.u;
}

// dtype probe (verified) — all threads of the block must call.
__device__ __forceinline__ int computeIsF32(const u16* y, int* cnt, int t) {
    if (t == 0) *cnt = 0;
    __syncthreads();
    if (t < 256) {
        u16 v = y[2 * t];
        int e = (v >> 7) & 0xFF;
        if (v == 0 || (e >= 96 && e < 160)) atomicAdd(cnt, 1);
    }
    __syncthreads();
    return (*cnt < 192) ? 1 : 0;
}

// ---------------------------------------------------------------------------
// Kernel 1: pack — verbatim R0 (verified).
// ---------------------------------------------------------------------------
__global__ __launch_bounds__(256) void pack_kernel(
    const void* __restrict__ yhat,
    const void* __restrict__ Ws1, const void* __restrict__ Wc1,
    const void* __restrict__ Wb1, const void* __restrict__ Ws2,
    const void* __restrict__ Wc2,
    const void* __restrict__ bs1, const void* __restrict__ bc1,
    const void* __restrict__ bb1, const void* __restrict__ bs2,
    const void* __restrict__ bc2, const void* __restrict__ bb2,
    u16* __restrict__ WallT, u16* __restrict__ W2T, float* __restrict__ biasF)
{
    __shared__ int fcnt;
    const int bid = blockIdx.x, t = threadIdx.x;
    const int isF32 = computeIsF32((const u16*)yhat, &fcnt, t);
    if (bid < 64) {
        __shared__ u16 tile[64][65];
        const int c0 = (bid & 15) * 64;      // col-tile in [0,1024)
        const int k0 = (bid >> 4) * 64;      // k-tile in [0,256)
        const void* src; int coff; int roff = 0;
        if (c0 < 256)      { src = Ws1; coff = c0; }
        else if (c0 < 512) { src = Wc1; coff = c0 - 256; }
        else if (c0 < 768) { src = Wb1; coff = c0 - 512; }
        else               { src = Wb1; coff = c0 - 768; roff = 256; }
        const int cc = t & 63, kk0 = t >> 6;
        #pragma unroll
        for (int i = 0; i < 16; ++i) {
            int kk = kk0 + i * 4;
            tile[kk][cc] = ldW(src, (k0 + kk + roff) * 256 + coff + cc, isF32);
        }
        __syncthreads();
        const int kk2 = t & 63, cc0 = t >> 6;
        #pragma unroll
        for (int i = 0; i < 16; ++i) {
            int cc2 = cc0 + i * 4;
            WallT[(c0 + cc2) * 256 + (k0 + kk2)] = tile[kk2][cc2];
        }
    } else if (bid < 128) {
        int e2 = (bid - 64) * 256 + t;       // < 16384
        int c = e2 >> 8, k = e2 & 255;
        u16 v = 0;
        if (c < 40)                 v = ldW(Ws2, k * 40 + c, isF32);
        else if (c >= 48 && c < 53) v = ldW(Wc2, k * 5 + (c - 48), isF32);
        W2T[c * 256 + k] = v;
    } else {
        int idx = (bid - 128) * 256 + t;     // < 1024
        float v = 0.f;
        if (idx < 256)       v = ldF(bs1, idx, isF32);
        else if (idx < 512)  v = ldF(bc1, idx - 256, isF32);
        else if (idx < 768)  v = ldF(bb1, idx - 512, isF32);
        else if (idx < 808)  v = ldF(bs2, idx - 768, isF32);
        else if (idx < 813)  v = ldF(bc2, idx - 808, isF32);
        else if (idx >= 816 && idx < 821) v = ldF(bb2, idx - 816, isF32);
        biasF[idx] = v;
    }
}

// ---------------------------------------------------------------------------
// Kernel 2 (NEW): fused2 — 3 blocks/CU via LDS union 53.3 KB.
//   bonds (bid<256): P2 half of L1 goes to per-molecule WORKSPACE (fp16,
//     [48][256]); block re-reads its own slice (visible across the
//     __syncthreads; L2-resident). LDS = Xm + P1L + WsB = 53,328 B.
//   heads32 (bid in [256,896)): 32-row tiles, both-math verbatim heads.
//     LDS = Xs[32] + Hb[32] = 33,792 B. hb%320 -> tile, hb/320 -> head.
// Union 53,328 B -> 3 blocks/CU (24 waves, was 16) if VGPR <= 85.
// ---------------------------------------------------------------------------
union Shared2 {
    struct { u16 Xm[48 * SK]; u16 P1L[48 * SK]; u16 WsB[5 * 264]; } bd; // 53,328 B
    struct { u16 Xs[32 * SK]; u16 Hb[32 * SK]; } hd;                    // 33,792 B
};

__global__ __launch_bounds__(512) void fused2_kernel(
    const void* __restrict__ Xv, const u16* __restrict__ WallT,
    const u16* __restrict__ W2T, const void* __restrict__ Wb2,
    const float* __restrict__ biasF, u16* __restrict__ P2g,
    void* __restrict__ outv)
{
    __shared__ Shared2 sh;
    __shared__ int fcnt;
    const int t = threadIdx.x;
    const int bid = blockIdx.x;
    const int isF32 = computeIsF32((const u16*)Xv, &fcnt, t);

    const int w = t >> 6, l = t & 63;
    const int ml = l & 15, kq = l >> 4, r0 = kq * 4;

    if (bid < 256) {
        // =================== bonds body ===================
        const int b = bid;                 // molecule
        u16* __restrict__ pg = P2g + (size_t)b * 12288;   // [48][256] fp16

        if (isF32) {   // stage X rows 0..39 (fp32 -> bf16), zero rows 40..47
            const floatx4* __restrict__ src = (const floatx4*)((const float*)Xv + b * 10240);
            #pragma unroll
            for (int s = 0; s < 5; ++s) {
                int cid = t + s * 512;             // 2560 chunks of 4 floats
                int row = cid >> 6, ch = cid & 63;
                floatx4 f = src[cid];
                ushort4v u;
                u[0] = f2bf(f[0]); u[1] = f2bf(f[1]); u[2] = f2bf(f[2]); u[3] = f2bf(f[3]);
                *(ushort4v*)&sh.bd.Xm[row * SK + ch * 4] = u;
            }
            {   // zero rows 40..47
                int row = 40 + (t >> 6), ch = t & 63;
                ushort4v z = {0, 0, 0, 0};
                *(ushort4v*)&sh.bd.Xm[row * SK + ch * 4] = z;
            }
        } else {
            const int4v* __restrict__ src = (const int4v*)((const u16*)Xv + b * 10240);
            #pragma unroll
            for (int s = 0; s < 3; ++s) {
                int cid = t + s * 512;             // < 1536
                int row = cid >> 5, ch = cid & 31;
                if (cid < 1280) *(int4v*)&sh.bd.Xm[row * SK + ch * 8] = src[cid];
                else { int4v z = {0, 0, 0, 0}; *(int4v*)&sh.bd.Xm[row * SK + ch * 8] = z; }
            }
        }
        // Wb2[256][5] -> WsB[c][k] fp16, c<5
        #pragma unroll
        for (int s = 0; s < 3; ++s) {
            int e2 = t + s * 512;                  // < 1536
            if (e2 < 1280) {
                int c = e2 >> 8, k = e2 & 255;
                sh.bd.WsB[c * 264 + k] = ldWh(Wb2, k * 5 + c, isF32);
            }
        }
        __syncthreads();   // Xm + WsB visible

        // ---- layer 1 (R17 math): P = X @ Wb1 (+bb1 on P1), fp16 out.
        //      gc<256 -> P1L (LDS); gc>=256 -> P2g (workspace, bias 0).
        for (int n = 0; n < 4; ++n) {
            const int gc = (w + 8 * n) * 16 + ml;  // [0,512), wave-uniform split
            floatx4 acc[3] = {};
            #pragma unroll
            for (int ks = 0; ks < 8; ++ks) {
                const int k0 = ks * 32 + kq * 8;
                bf16x8 bf = *(const bf16x8*)&WallT[(512 + gc) * 256 + k0];
                #pragma unroll
                for (int i = 0; i < 3; ++i) {
                    bf16x8 a = *(const bf16x8*)&sh.bd.Xm[(i * 16 + ml) * SK + k0];
                    acc[i] = __builtin_amdgcn_mfma_f32_16x16x32_bf16(a, bf, acc[i], 0, 0, 0);
                }
            }
            if (gc < 256) {
                const float bias = biasF[512 + gc];
                #pragma unroll
                for (int i = 0; i < 3; ++i)
                    #pragma unroll
                    for (int r = 0; r < 4; ++r)
                        sh.bd.P1L[(i * 16 + r0 + r) * SK + gc] = f2h_bits(acc[i][r] + bias);
            } else {
                const int col = gc - 256;
                #pragma unroll
                for (int i = 0; i < 3; ++i)
                    #pragma unroll
                    for (int r = 0; r < 4; ++r)
                        pg[(i * 16 + r0 + r) * 256 + col] = f2h_bits(acc[i][r]);
            }
        }
        __syncthreads();   // P1L (LDS) + P2g (global, block-local) visible

        // ---- symmetric-fused pair phase, packed f16, jt-grouped (R17) ----
        const int sel = (ml < 5) ? ml : 4;         // ml>=5 feeds discarded D cols
        half8 wf[8];
        #pragma unroll
        for (int ks = 0; ks < 8; ++ks)
            wf[ks] = *(const half8*)&sh.bd.WsB[sel * 264 + ks * 32 + kq * 8];
        const float b2x2 = 2.f * biasF[816 + ml];  // ml>=5 reads zeros (in-bounds)
        const _Float16 c001 = (_Float16)0.01f;

        // per-job store (identical to R10/R17)
        auto storeJob = [&](int i, int jt, const floatx4& acc) {
            if (ml < 5) {                          // D: row=kq*4+r -> j, col=ml -> class
                const bool diag = (jt == (i >> 4));
                #pragma unroll
                for (int r = 0; r < 4; ++r) {
                    const int j = jt * 16 + r0 + r;
                    if (j < 40 && (!diag || j >= i)) {
                        const float v = acc[r] + b2x2;
                        const int o1 = 460800 + (b * 1600 + i * 40 + j) * 5 + ml;
                        if (isF32) ((float*)outv)[o1] = v;
                        else ((__hip_bfloat16*)outv)[o1] = __float2bfloat16(v);
                        if (!diag || j > i) {
                            const int o2 = 460800 + (b * 1600 + j * 40 + i) * 5 + ml;
                            if (isF32) ((float*)outv)[o2] = v;
                            else ((__hip_bfloat16*)outv)[o2] = __float2bfloat16(v);
                        }
                    }
                }
            }
        };

        // jt-group (R17): b1 (LDS) / b2 (global) once per (jt,ks), shared
        // across the nm i-chains; a1 from LDS, a2 from global (L2-hot slice).
        auto runGroup = [&](const int jt, const int nm) {
            floatx4 acc[5] = {};
            #pragma unroll
            for (int ks = 0; ks < 8; ++ks) {
                const int k0 = ks * 32 + kq * 8;
                const uint4v b1 = *(const uint4v*)&sh.bd.P1L[(jt * 16 + ml) * SK + k0];
                const uint4v b2 = *(const uint4v*)&pg[(jt * 16 + ml) * 256 + k0];
                #pragma unroll
                for (int mm = 0; mm < 5; ++mm) {
                    if (mm < nm) {
                        const int i = w + 8 * mm;   // [0,40)
                        const uint4v a1 = *(const uint4v*)&sh.bd.P1L[i * SK + k0];
                        const uint4v a2 = *(const uint4v*)&pg[i * 256 + k0];
                        union { unsigned int u[4]; half8 v; } af;
                        #pragma unroll
                        for (int d = 0; d < 4; ++d) {
                            const half2v tF = u2h2(a1[d]) + u2h2(b2[d]);   // v_pk_add_f16
                            const half2v tB = u2h2(b1[d]) + u2h2(a2[d]);
                            const half2v lF = __builtin_elementwise_max(tF, tF * c001);
                            const half2v lB = __builtin_elementwise_max(tB, tB * c001);
                            af.u[d] = h22u(lF + lB);
                        }
                        acc[mm] = __builtin_amdgcn_mfma_f32_16x16x32_f16(af.v, wf[ks], acc[mm], 0, 0, 0);
                    }
                }
            }
            #pragma unroll
            for (int mm = 0; mm < 5; ++mm)
                if (mm < nm) storeJob(w + 8 * mm, jt, acc[mm]);
        };

        // all 11 jobs (R17-verified): jt=0 -> m{0,1}; jt=1 -> m{0..3}; jt=2 -> m{0..4}
        runGroup(0, 2);
        runGroup(1, 4);
        runGroup(2, 5);
    } else {
        // =================== heads32 body ===================
        const int hb = bid - 256;              // [0,640)
        const int bm0 = (hb % 320) * 32;
        const int head = hb / 320;

        if (isF32) {   // stage X tile [32][256] from fp32, cvt to bf16
            const floatx4* __restrict__ src = (const floatx4*)((const float*)Xv + bm0 * 256);
            #pragma unroll
            for (int s = 0; s < 4; ++s) {
                int cid = t + s * 512;             // < 2048 chunks of 4 floats
                int row = cid >> 6, ch = cid & 63;
                floatx4 f = src[cid];
                ushort4v u;
                u[0] = f2bf(f[0]); u[1] = f2bf(f[1]); u[2] = f2bf(f[2]); u[3] = f2bf(f[3]);
                *(ushort4v*)&sh.hd.Xs[row * SK + ch * 4] = u;
            }
        } else {       // stage X tile from bf16
            const int4v* __restrict__ src = (const int4v*)((const u16*)Xv + bm0 * 256);
            #pragma unroll
            for (int s = 0; s < 2; ++s) {
                int cid = t + s * 512;             // < 1024 chunks of 8 bf16
                int row = cid >> 5, ch = cid & 31;
                *(int4v*)&sh.hd.Xs[row * SK + ch * 8] = src[cid];
            }
        }
        __syncthreads();

        // ---- layer 1: 16 col-tiles over 8 waves; 2 M-tiles each ----
        #pragma unroll
        for (int n = 0; n < 2; ++n) {
            const int ct = w + 8 * n;              // [0,16)
            floatx4 acc[2] = {};
            #pragma unroll
            for (int ks = 0; ks < 8; ++ks) {
                const int k0 = ks * 32 + kq * 8;
                bf16x8 bf = *(const bf16x8*)&WallT[(head * 256 + ct * 16 + ml) * 256 + k0];
                #pragma unroll
                for (int mt = 0; mt < 2; ++mt) {
                    bf16x8 a = *(const bf16x8*)&sh.hd.Xs[(mt * 16 + ml) * SK + k0];
                    acc[mt] = __builtin_amdgcn_mfma_f32_16x16x32_bf16(a, bf, acc[mt], 0, 0, 0);
                }
            }
            const int col = ct * 16 + ml;          // [0,256)
            const float bias = biasF[head * 256 + col];   // bs1 | bc1
            #pragma unroll
            for (int mt = 0; mt < 2; ++mt)
                #pragma unroll
                for (int r = 0; r < 4; ++r)
                    sh.hd.Hb[(mt * 16 + r0 + r) * SK + col] = f2bf(lrelu(acc[mt][r] + bias));
        }
        __syncthreads();   // Hb complete

        // ---- layer 2: waves 0,1 own M-tiles 0,1 ----
        if (w < 2) {
            const int nct = (head == 0) ? 3 : 1;   // block-uniform
            const int c0  = (head == 0) ? 0 : 48;
            floatx4 acc2[3] = {};
            #pragma unroll
            for (int ks = 0; ks < 8; ++ks) {
                const int k0 = ks * 32 + kq * 8;
                bf16x8 a = *(const bf16x8*)&sh.hd.Hb[(w * 16 + ml) * SK + k0];
                #pragma unroll
                for (int j = 0; j < 3; ++j) {
                    if (j < nct) {
                        bf16x8 bf = *(const bf16x8*)&W2T[(c0 + j * 16 + ml) * 256 + k0];
                        acc2[j] = __builtin_amdgcn_mfma_f32_16x16x32_bf16(a, bf, acc2[j], 0, 0, 0);
                    }
                }
            }
            #pragma unroll
            for (int j = 0; j < 3; ++j) {
                if (j < nct) {
                    const int col = j * 16 + ml;
                    const int lim = (head == 0) ? 40 : 5;
                    if (col < lim) {
                        const float bias = biasF[(head == 0 ? 768 : 808) + col];
                        #pragma unroll
                        for (int r = 0; r < 4; ++r) {
                            const int row = bm0 + w * 16 + r0 + r;
                            const int o = (head == 0) ? row * 40 + col
                                                      : 409600 + row * 5 + col;
                            const float v = acc2[j][r] + bias;
                            if (isF32) ((float*)outv)[o] = v;
                            else ((__hip_bfloat16*)outv)[o] = __float2bfloat16(v);
                        }
                    }
                }
            }
        }
    }
}

// ---------------------------------------------------------------------------
// Kernel 2 (FALLBACK): fused — verbatim R17 (verified, 122.7 us total).
// ---------------------------------------------------------------------------
union SharedHB {
    struct { u16 Xs[64 * SK]; u16 Hb[64 * SK]; } hd;                        // 67584 B
    struct { u16 Xm[48 * SK]; u16 P1L[48 * SK]; u16 P2L[48 * SK];
             u16 WsB[5 * 264]; } bd;                                       // 78672 B
};

__global__ __launch_bounds__(512) void fused_kernel(
    const void* __restrict__ Xv, const u16* __restrict__ WallT,
    const u16* __restrict__ W2T, const void* __restrict__ Wb2,
    const float* __restrict__ biasF, void* __restrict__ outv)
{
    __shared__ SharedHB sh;
    __shared__ int fcnt;
    const int t = threadIdx.x;
    const int bid = blockIdx.x;
    const int isF32 = computeIsF32((const u16*)Xv, &fcnt, t);

    const int w = t >> 6, l = t & 63;
    const int ml = l & 15, kq = l >> 4, r0 = kq * 4;

    if (bid < 256) {
        const int b = bid;

        if (isF32) {
            const floatx4* __restrict__ src = (const floatx4*)((const float*)Xv + b * 10240);
            #pragma unroll
            for (int s = 0; s < 5; ++s) {
                int cid = t + s * 512;
                int row = cid >> 6, ch = cid & 63;
                floatx4 f = src[cid];
                ushort4v u;
                u[0] = f2bf(f[0]); u[1] = f2bf(f[1]); u[2] = f2bf(f[2]); u[3] = f2bf(f[3]);
                *(ushort4v*)&sh.bd.Xm[row * SK + ch * 4] = u;
            }
            {
                int row = 40 + (t >> 6), ch = t & 63;
                ushort4v z = {0, 0, 0, 0};
                *(ushort4v*)&sh.bd.Xm[row * SK + ch * 4] = z;
            }
        } else {
            const int4v* __restrict__ src = (const int4v*)((const u16*)Xv + b * 10240);
            #pragma unroll
            for (int s = 0; s < 3; ++s) {
                int cid = t + s * 512;
                int row = cid >> 5, ch = cid & 31;
                if (cid < 1280) *(int4v*)&sh.bd.Xm[row * SK + ch * 8] = src[cid];
                else { int4v z = {0, 0, 0, 0}; *(int4v*)&sh.bd.Xm[row * SK + ch * 8] = z; }
            }
        }
        #pragma unroll
        for (int s = 0; s < 3; ++s) {
            int e2 = t + s * 512;
            if (e2 < 1280) {
                int c = e2 >> 8, k = e2 & 255;
                sh.bd.WsB[c * 264 + k] = ldWh(Wb2, k * 5 + c, isF32);
            }
        }
        __syncthreads();

        for (int n = 0; n < 4; ++n) {
            const int gc = (w + 8 * n) * 16 + ml;
            floatx4 acc[3] = {};
            #pragma unroll
            for (int ks = 0; ks < 8; ++ks) {
                const int k0 = ks * 32 + kq * 8;
                bf16x8 bf = *(const bf16x8*)&WallT[(512 + gc) * 256 + k0];
                #pragma unroll
                for (int i = 0; i < 3; ++i) {
                    bf16x8 a = *(const bf16x8*)&sh.bd.Xm[(i * 16 + ml) * SK + k0];
                    acc[i] = __builtin_amdgcn_mfma_f32_16x16x32_bf16(a, bf, acc[i], 0, 0, 0);
                }
            }
            u16* dst = (gc < 256) ? sh.bd.P1L : sh.bd.P2L;
            const int col = gc & 255;
            const float bias = (gc < 256) ? biasF[512 + gc] : 0.f;
            #pragma unroll
            for (int i = 0; i < 3; ++i)
                #pragma unroll
                for (int r = 0; r < 4; ++r)
                    dst[(i * 16 + r0 + r) * SK + col] = f2h_bits(acc[i][r] + bias);
        }
        __syncthreads();

        const int sel = (ml < 5) ? ml : 4;
        half8 wf[8];
        #pragma unroll
        for (int ks = 0; ks < 8; ++ks)
            wf[ks] = *(const half8*)&sh.bd.WsB[sel * 264 + ks * 32 + kq * 8];
        const float b2x2 = 2.f * biasF[816 + ml];
        const _Float16 c001 = (_Float16)0.01f;

        auto storeJob = [&](int i, int jt, const floatx4& acc) {
            if (ml < 5) {
                const bool diag = (jt == (i >> 4));
                #pragma unroll
                for (int r = 0; r < 4; ++r) {
                    const int j = jt * 16 + r0 + r;
                    if (j < 40 && (!diag || j >= i)) {
                        const float v = acc[r] + b2x2;
                        const int o1 = 460800 + (b * 1600 + i * 40 + j) * 5 + ml;
                        if (isF32) ((float*)outv)[o1] = v;
                        else ((__hip_bfloat16*)outv)[o1] = __float2bfloat16(v);
                        if (!diag || j > i) {
                            const int o2 = 460800 + (b * 1600 + j * 40 + i) * 5 + ml;
                            if (isF32) ((float*)outv)[o2] = v;
                            else ((__hip_bfloat16*)outv)[o2] = __float2bfloat16(v);
                        }
                    }
                }
            }
        };

        auto runGroup = [&](const int jt, const int nm) {
            floatx4 acc[5] = {};
            #pragma unroll
            for (int ks = 0; ks < 8; ++ks) {
                const int k0 = ks * 32 + kq * 8;
                const uint4v b1 = *(const uint4v*)&sh.bd.P1L[(jt * 16 + ml) * SK + k0];
                const uint4v b2 = *(const uint4v*)&sh.bd.P2L[(jt * 16 + ml) * SK + k0];
                #pragma unroll
                for (int mm = 0; mm < 5; ++mm) {
                    if (mm < nm) {
                        const int i = w + 8 * mm;
                        const uint4v a1 = *(const uint4v*)&sh.bd.P1L[i * SK + k0];
                        const uint4v a2 = *(const uint4v*)&sh.bd.P2L[i * SK + k0];
                        union { unsigned int u[4]; half8 v; } af;
                        #pragma unroll
                        for (int d = 0; d < 4; ++d) {
                            const half2v tF = u2h2(a1[d]) + u2h2(b2[d]);
                            const half2v tB = u2h2(b1[d]) + u2h2(a2[d]);
                            const half2v lF = __builtin_elementwise_max(tF, tF * c001);
                            const half2v lB = __builtin_elementwise_max(tB, tB * c001);
                            af.u[d] = h22u(lF + lB);
                        }
                        acc[mm] = __builtin_amdgcn_mfma_f32_16x16x32_f16(af.v, wf[ks], acc[mm], 0, 0, 0);
                    }
                }
            }
            #pragma unroll
            for (int mm = 0; mm < 5; ++mm)
                if (mm < nm) storeJob(w + 8 * mm, jt, acc[mm]);
        };

        runGroup(0, 2);
        runGroup(1, 4);
        runGroup(2, 5);
    } else {
        const int hb = bid - 256;
        const int bm0 = (hb % 160) * 64;
        const int head = hb / 160;

        if (isF32) {
            const floatx4* __restrict__ src = (const floatx4*)((const float*)Xv + bm0 * 256);
            #pragma unroll
            for (int s = 0; s < 8; ++s) {
                int cid = t + s * 512;
                int row = cid >> 6, ch = cid & 63;
                floatx4 f = src[cid];
                ushort4v u;
                u[0] = f2bf(f[0]); u[1] = f2bf(f[1]); u[2] = f2bf(f[2]); u[3] = f2bf(f[3]);
                *(ushort4v*)&sh.hd.Xs[row * SK + ch * 4] = u;
            }
        } else {
            const int4v* __restrict__ src = (const int4v*)((const u16*)Xv + bm0 * 256);
            #pragma unroll
            for (int s = 0; s < 4; ++s) {
                int cid = t + s * 512;
                int row = cid >> 5, ch = cid & 31;
                *(int4v*)&sh.hd.Xs[row * SK + ch * 8] = src[cid];
            }
        }
        __syncthreads();

        #pragma unroll
        for (int n = 0; n < 2; ++n) {
            const int ct = w + 8 * n;
            floatx4 acc[4] = {};
            #pragma unroll
            for (int ks = 0; ks < 8; ++ks) {
                const int k0 = ks * 32 + kq * 8;
                bf16x8 bf = *(const bf16x8*)&WallT[(head * 256 + ct * 16 + ml) * 256 + k0];
                #pragma unroll
                for (int mt = 0; mt < 4; ++mt) {
                    bf16x8 a = *(const bf16x8*)&sh.hd.Xs[(mt * 16 + ml) * SK + k0];
                    acc[mt] = __builtin_amdgcn_mfma_f32_16x16x32_bf16(a, bf, acc[mt], 0, 0, 0);
                }
            }
            const int col = ct * 16 + ml;
            const float bias = biasF[head * 256 + col];
            #pragma unroll
            for (int mt = 0; mt < 4; ++mt)
                #pragma unroll
                for (int r = 0; r < 4; ++r)
                    sh.hd.Hb[(mt * 16 + r0 + r) * SK + col] = f2bf(lrelu(acc[mt][r] + bias));
        }
        __syncthreads();

        if (w < 4) {
            const int nct = (head == 0) ? 3 : 1;
            const int c0  = (head == 0) ? 0 : 48;
            floatx4 acc2[3] = {};
            #pragma unroll
            for (int ks = 0; ks < 8; ++ks) {
                const int k0 = ks * 32 + kq * 8;
                bf16x8 a = *(const bf16x8*)&sh.hd.Hb[(w * 16 + ml) * SK + k0];
                #pragma unroll
                for (int j = 0; j < 3; ++j) {
                    if (j < nct) {
                        bf16x8 bf = *(const bf16x8*)&W2T[(c0 + j * 16 + ml) * 256 + k0];
                        acc2[j] = __builtin_amdgcn_mfma_f32_16x16x32_bf16(a, bf, acc2[j], 0, 0, 0);
                    }
                }
            }
            #pragma unroll
            for (int j = 0; j < 3; ++j) {
                if (j < nct) {
                    const int col = j * 16 + ml;
                    const int lim = (head == 0) ? 40 : 5;
                    if (col < lim) {
                        const float bias = biasF[(head == 0 ? 768 : 808) + col];
                        #pragma unroll
                        for (int r = 0; r < 4; ++r) {
                            const int row = bm0 + w * 16 + r0 + r;
                            const int o = (head == 0) ? row * 40 + col
                                                      : 409600 + row * 5 + col;
                            const float v = acc2[j][r] + bias;
                            if (isF32) ((float*)outv)[o] = v;
                            else ((__hip_bfloat16*)outv)[o] = __float2bfloat16(v);
                        }
                    }
                }
            }
        }
    }
}

// ---------------------------------------------------------------------------
extern "C" void kernel_launch(void* const* d_in, const int* in_sizes, int n_in,
                              void* d_out, int out_size, void* d_ws, size_t ws_size,
                              hipStream_t stream)
{
    const void* yhat = d_in[0];
    const void* Ws1  = d_in[1];
    const void* bs1  = d_in[2];
    const void* Ws2  = d_in[3];
    const void* bs2  = d_in[4];
    const void* Wc1  = d_in[5];
    const void* bc1  = d_in[6];
    const void* Wc2  = d_in[7];
    const void* bc2  = d_in[8];
    const void* Wb1  = d_in[9];
    const void* bb1  = d_in[10];
    const void* Wb2  = d_in[11];
    const void* bb2  = d_in[12];

    // workspace:
    //   [4096, 8192)        biasF  (1024 f32)
    //   [8192, 40960)       W2T    (64*256 bf16)
    //   [40960, 565248)     WallT  (1024*256 bf16)
    //   [565248, 6856704)   P2g    (256 mol x 48 x 256 fp16)
    char* wsb = (char*)d_ws;
    float* biasF = (float*)(wsb + 4096);
    u16*   W2T   = (u16*)(wsb + 8192);
    u16*   WallT = (u16*)(wsb + 40960);
    u16*   P2g   = (u16*)(wsb + 565248);
    const bool big = ws_size >= 565248 + (size_t)256 * 12288 * 2;  // 6,856,704 B

    pack_kernel<<<132, 256, 0, stream>>>(yhat, Ws1, Wc1, Wb1, Ws2, Wc2,
                                         bs1, bc1, bb1, bs2, bc2, bb2,
                                         WallT, W2T, biasF);
    if (big) {
        fused2_kernel<<<896, 512, 0, stream>>>(yhat, WallT, W2T, Wb2, biasF,
                                               P2g, d_out);
    } else {
        fused_kernel<<<576, 512, 0, stream>>>(yhat, WallT, W2T, Wb2, biasF, d_out);
    }
}

// Round 19
// 125.620 us; speedup vs baseline: 1.0794x; 1.0794x over previous
//
#include <hip/hip_runtime.h>
#include <hip/hip_bf16.h>

typedef unsigned short u16;
typedef __attribute__((ext_vector_type(4))) int   int4v;
typedef __attribute__((ext_vector_type(4))) unsigned int uint4v;
typedef __attribute__((ext_vector_type(4))) unsigned short ushort4v;
typedef __attribute__((ext_vector_type(4))) float floatx4;
typedef __attribute__((ext_vector_type(8))) short bf16x8;
typedef _Float16 half8 __attribute__((ext_vector_type(8)));
typedef _Float16 half2v __attribute__((ext_vector_type(2)));

#define LRELU_NS 0.01f
#define SK 264   // LDS k-stride (u16 units): 256 + 8 pad, 16B-aligned rows

__device__ __forceinline__ float bitsToF(unsigned int b) {
    union { unsigned int u; float f; } v; v.u = b << 16; return v.f;
}
__device__ __forceinline__ u16 f2bf(float f) {
    __hip_bfloat16 h = __float2bfloat16(f);
    return *reinterpret_cast<u16*>(&h);
}
// 2-op leaky relu (f32): max(x, 0.01x) — exact for all finite x
__device__ __forceinline__ float lrelu(float v) {
    return fmaxf(v, LRELU_NS * v);
}
__device__ __forceinline__ u16 ldW(const void* p, int i, int isF32) {
    return isF32 ? f2bf(((const float*)p)[i]) : ((const u16*)p)[i];
}
__device__ __forceinline__ float ldF(const void* p, int i, int isF32) {
    return isF32 ? ((const float*)p)[i]
                 : bitsToF((unsigned int)((const u16*)p)[i]);
}
// float -> fp16 bits (native _Float16 cast = round-to-nearest-even)
__device__ __forceinline__ u16 f2h_bits(float f) {
    union { _Float16 h; u16 u; } v; v.h = (_Float16)f; return v.u;
}
// load -> fp16 bits (for the f16 pair path)
__device__ __forceinline__ u16 ldWh(const void* p, int i, int isF32) {
    float f = isF32 ? ((const float*)p)[i]
                    : bitsToF((unsigned int)((const u16*)p)[i]);
    return f2h_bits(f);
}
__device__ __forceinline__ half2v u2h2(unsigned int x) {
    union { unsigned int u; half2v h; } v; v.u = x; return v.h;
}
__device__ __forceinline__ unsigned int h22u(half2v x) {
    union { half2v h; unsigned int u; } v; v.h = x; return v.u;
}

// dtype probe (verified) — all threads of the block must call.
__device__ __forceinline__ int computeIsF32(const u16* y, int* cnt, int t) {
    if (t == 0) *cnt = 0;
    __syncthreads();
    if (t < 256) {
        u16 v = y[2 * t];
        int e = (v >> 7) & 0xFF;
        if (v == 0 || (e >= 96 && e < 160)) atomicAdd(cnt, 1);
    }
    __syncthreads();
    return (*cnt < 192) ? 1 : 0;
}

// ---------------------------------------------------------------------------
// Kernel 1: pack — verbatim R0 (verified).
// ---------------------------------------------------------------------------
__global__ __launch_bounds__(256) void pack_kernel(
    const void* __restrict__ yhat,
    const void* __restrict__ Ws1, const void* __restrict__ Wc1,
    const void* __restrict__ Wb1, const void* __restrict__ Ws2,
    const void* __restrict__ Wc2,
    const void* __restrict__ bs1, const void* __restrict__ bc1,
    const void* __restrict__ bb1, const void* __restrict__ bs2,
    const void* __restrict__ bc2, const void* __restrict__ bb2,
    u16* __restrict__ WallT, u16* __restrict__ W2T, float* __restrict__ biasF)
{
    __shared__ int fcnt;
    const int bid = blockIdx.x, t = threadIdx.x;
    const int isF32 = computeIsF32((const u16*)yhat, &fcnt, t);
    if (bid < 64) {
        __shared__ u16 tile[64][65];
        const int c0 = (bid & 15) * 64;      // col-tile in [0,1024)
        const int k0 = (bid >> 4) * 64;      // k-tile in [0,256)
        const void* src; int coff; int roff = 0;
        if (c0 < 256)      { src = Ws1; coff = c0; }
        else if (c0 < 512) { src = Wc1; coff = c0 - 256; }
        else if (c0 < 768) { src = Wb1; coff = c0 - 512; }
        else               { src = Wb1; coff = c0 - 768; roff = 256; }
        const int cc = t & 63, kk0 = t >> 6;
        #pragma unroll
        for (int i = 0; i < 16; ++i) {
            int kk = kk0 + i * 4;
            tile[kk][cc] = ldW(src, (k0 + kk + roff) * 256 + coff + cc, isF32);
        }
        __syncthreads();
        const int kk2 = t & 63, cc0 = t >> 6;
        #pragma unroll
        for (int i = 0; i < 16; ++i) {
            int cc2 = cc0 + i * 4;
            WallT[(c0 + cc2) * 256 + (k0 + kk2)] = tile[kk2][cc2];
        }
    } else if (bid < 128) {
        int e2 = (bid - 64) * 256 + t;       // < 16384
        int c = e2 >> 8, k = e2 & 255;
        u16 v = 0;
        if (c < 40)                 v = ldW(Ws2, k * 40 + c, isF32);
        else if (c >= 48 && c < 53) v = ldW(Wc2, k * 5 + (c - 48), isF32);
        W2T[c * 256 + k] = v;
    } else {
        int idx = (bid - 128) * 256 + t;     // < 1024
        float v = 0.f;
        if (idx < 256)       v = ldF(bs1, idx, isF32);
        else if (idx < 512)  v = ldF(bc1, idx - 256, isF32);
        else if (idx < 768)  v = ldF(bb1, idx - 512, isF32);
        else if (idx < 808)  v = ldF(bs2, idx - 768, isF32);
        else if (idx < 813)  v = ldF(bc2, idx - 808, isF32);
        else if (idx >= 816 && idx < 821) v = ldF(bb2, idx - 816, isF32);
        biasF[idx] = v;
    }
}

// ---------------------------------------------------------------------------
// Kernel 2: fused — R17 structure with ONE delta: each heads block computes
// BOTH heads (block-uniform head loop) off a single X staging. Grid shrinks
// 576 -> 416 (<= 512 slots: no second dispatch round, no tail), and heads
// X-staging count halves (320 -> 160). All math bodies verbatim R17.
//   bid in [0,256):   bonds — mol = bid; jt-grouped pair phase (R17).
//   bid in [256,416): heads — bm0 = (bid-256)*64; head = 0 then 1.
// LDS = union(78.7 KB bonds, 67.6 KB heads) -> 2 blocks/CU (as R17).
// ---------------------------------------------------------------------------
union SharedHB {
    struct { u16 Xs[64 * SK]; u16 Hb[64 * SK]; } hd;                        // 67584 B
    struct { u16 Xm[48 * SK]; u16 P1L[48 * SK]; u16 P2L[48 * SK];
             u16 WsB[5 * 264]; } bd;                                       // 78672 B
};

__global__ __launch_bounds__(512) void fused_kernel(
    const void* __restrict__ Xv, const u16* __restrict__ WallT,
    const u16* __restrict__ W2T, const void* __restrict__ Wb2,
    const float* __restrict__ biasF, void* __restrict__ outv)
{
    __shared__ SharedHB sh;
    __shared__ int fcnt;
    const int t = threadIdx.x;
    const int bid = blockIdx.x;
    const int isF32 = computeIsF32((const u16*)Xv, &fcnt, t);

    const int w = t >> 6, l = t & 63;
    const int ml = l & 15, kq = l >> 4, r0 = kq * 4;

    if (bid < 256) {
        // =================== bonds body (verbatim R17) ===================
        const int b = bid;                 // molecule

        if (isF32) {   // stage X rows 0..39 (fp32 -> bf16), zero rows 40..47
            const floatx4* __restrict__ src = (const floatx4*)((const float*)Xv + b * 10240);
            #pragma unroll
            for (int s = 0; s < 5; ++s) {
                int cid = t + s * 512;             // 2560 chunks of 4 floats
                int row = cid >> 6, ch = cid & 63;
                floatx4 f = src[cid];
                ushort4v u;
                u[0] = f2bf(f[0]); u[1] = f2bf(f[1]); u[2] = f2bf(f[2]); u[3] = f2bf(f[3]);
                *(ushort4v*)&sh.bd.Xm[row * SK + ch * 4] = u;
            }
            {   // zero rows 40..47
                int row = 40 + (t >> 6), ch = t & 63;
                ushort4v z = {0, 0, 0, 0};
                *(ushort4v*)&sh.bd.Xm[row * SK + ch * 4] = z;
            }
        } else {
            const int4v* __restrict__ src = (const int4v*)((const u16*)Xv + b * 10240);
            #pragma unroll
            for (int s = 0; s < 3; ++s) {
                int cid = t + s * 512;             // < 1536
                int row = cid >> 5, ch = cid & 31;
                if (cid < 1280) *(int4v*)&sh.bd.Xm[row * SK + ch * 8] = src[cid];
                else { int4v z = {0, 0, 0, 0}; *(int4v*)&sh.bd.Xm[row * SK + ch * 8] = z; }
            }
        }
        // Wb2[256][5] -> WsB[c][k] fp16, c<5
        #pragma unroll
        for (int s = 0; s < 3; ++s) {
            int e2 = t + s * 512;                  // < 1536
            if (e2 < 1280) {
                int c = e2 >> 8, k = e2 & 255;
                sh.bd.WsB[c * 264 + k] = ldWh(Wb2, k * 5 + c, isF32);
            }
        }
        __syncthreads();   // Xm + WsB visible

        // ---- layer 1 (R10): P = X @ Wb1 (+bb1 on P1), fp16 out ----
        for (int n = 0; n < 4; ++n) {
            const int gc = (w + 8 * n) * 16 + ml;  // [0,512)
            floatx4 acc[3] = {};
            #pragma unroll
            for (int ks = 0; ks < 8; ++ks) {
                const int k0 = ks * 32 + kq * 8;
                bf16x8 bf = *(const bf16x8*)&WallT[(512 + gc) * 256 + k0];
                #pragma unroll
                for (int i = 0; i < 3; ++i) {
                    bf16x8 a = *(const bf16x8*)&sh.bd.Xm[(i * 16 + ml) * SK + k0];
                    acc[i] = __builtin_amdgcn_mfma_f32_16x16x32_bf16(a, bf, acc[i], 0, 0, 0);
                }
            }
            u16* dst = (gc < 256) ? sh.bd.P1L : sh.bd.P2L;
            const int col = gc & 255;
            const float bias = (gc < 256) ? biasF[512 + gc] : 0.f;   // bb1 on P1
            #pragma unroll
            for (int i = 0; i < 3; ++i)
                #pragma unroll
                for (int r = 0; r < 4; ++r)
                    dst[(i * 16 + r0 + r) * SK + col] = f2h_bits(acc[i][r] + bias);
        }
        __syncthreads();

        // ---- symmetric-fused pair phase, packed f16, jt-grouped (R17) ----
        const int sel = (ml < 5) ? ml : 4;         // ml>=5 feeds discarded D cols
        half8 wf[8];
        #pragma unroll
        for (int ks = 0; ks < 8; ++ks)
            wf[ks] = *(const half8*)&sh.bd.WsB[sel * 264 + ks * 32 + kq * 8];
        const float b2x2 = 2.f * biasF[816 + ml];  // ml>=5 reads zeros (in-bounds)
        const _Float16 c001 = (_Float16)0.01f;

        // per-job store (identical to R10/R17)
        auto storeJob = [&](int i, int jt, const floatx4& acc) {
            if (ml < 5) {                          // D: row=kq*4+r -> j, col=ml -> class
                const bool diag = (jt == (i >> 4));
                #pragma unroll
                for (int r = 0; r < 4; ++r) {
                    const int j = jt * 16 + r0 + r;
                    if (j < 40 && (!diag || j >= i)) {
                        const float v = acc[r] + b2x2;
                        const int o1 = 460800 + (b * 1600 + i * 40 + j) * 5 + ml;
                        if (isF32) ((float*)outv)[o1] = v;
                        else ((__hip_bfloat16*)outv)[o1] = __float2bfloat16(v);
                        if (!diag || j > i) {
                            const int o2 = 460800 + (b * 1600 + j * 40 + i) * 5 + ml;
                            if (isF32) ((float*)outv)[o2] = v;
                            else ((__hip_bfloat16*)outv)[o2] = __float2bfloat16(v);
                        }
                    }
                }
            }
        };

        // jt-group: b1/b2 loaded once per (jt,ks), shared across nm i-chains.
        auto runGroup = [&](const int jt, const int nm) {
            floatx4 acc[5] = {};
            #pragma unroll
            for (int ks = 0; ks < 8; ++ks) {
                const int k0 = ks * 32 + kq * 8;
                const uint4v b1 = *(const uint4v*)&sh.bd.P1L[(jt * 16 + ml) * SK + k0];
                const uint4v b2 = *(const uint4v*)&sh.bd.P2L[(jt * 16 + ml) * SK + k0];
                #pragma unroll
                for (int mm = 0; mm < 5; ++mm) {
                    if (mm < nm) {
                        const int i = w + 8 * mm;   // [0,40)
                        const uint4v a1 = *(const uint4v*)&sh.bd.P1L[i * SK + k0];
                        const uint4v a2 = *(const uint4v*)&sh.bd.P2L[i * SK + k0];
                        union { unsigned int u[4]; half8 v; } af;
                        #pragma unroll
                        for (int d = 0; d < 4; ++d) {
                            const half2v tF = u2h2(a1[d]) + u2h2(b2[d]);   // v_pk_add_f16
                            const half2v tB = u2h2(b1[d]) + u2h2(a2[d]);
                            const half2v lF = __builtin_elementwise_max(tF, tF * c001);
                            const half2v lB = __builtin_elementwise_max(tB, tB * c001);
                            af.u[d] = h22u(lF + lB);
                        }
                        acc[mm] = __builtin_amdgcn_mfma_f32_16x16x32_f16(af.v, wf[ks], acc[mm], 0, 0, 0);
                    }
                }
            }
            #pragma unroll
            for (int mm = 0; mm < 5; ++mm)
                if (mm < nm) storeJob(w + 8 * mm, jt, acc[mm]);
        };

        // all 11 jobs (R17-verified): jt=0 -> m{0,1}; jt=1 -> m{0..3}; jt=2 -> m{0..4}
        runGroup(0, 2);
        runGroup(1, 4);
        runGroup(2, 5);
    } else {
        // =================== heads body: BOTH heads per block ===================
        const int hb = bid - 256;              // [0,160)
        const int bm0 = hb * 64;

        if (isF32) {   // stage X tile [64][256] from fp32, cvt to bf16
            const floatx4* __restrict__ src = (const floatx4*)((const float*)Xv + bm0 * 256);
            #pragma unroll
            for (int s = 0; s < 8; ++s) {
                int cid = t + s * 512;             // < 4096 chunks of 4 floats
                int row = cid >> 6, ch = cid & 63;
                floatx4 f = src[cid];
                ushort4v u;
                u[0] = f2bf(f[0]); u[1] = f2bf(f[1]); u[2] = f2bf(f[2]); u[3] = f2bf(f[3]);
                *(ushort4v*)&sh.hd.Xs[row * SK + ch * 4] = u;
            }
        } else {       // stage X tile from bf16
            const int4v* __restrict__ src = (const int4v*)((const u16*)Xv + bm0 * 256);
            #pragma unroll
            for (int s = 0; s < 4; ++s) {
                int cid = t + s * 512;             // < 2048 chunks of 8 bf16
                int row = cid >> 5, ch = cid & 31;
                *(int4v*)&sh.hd.Xs[row * SK + ch * 8] = src[cid];
            }
        }
        __syncthreads();

        for (int head = 0; head < 2; ++head) {     // block-uniform loop
            // ---- layer 1: 16 col-tiles over 8 waves; 4 M-tiles each ----
            #pragma unroll
            for (int n = 0; n < 2; ++n) {
                const int ct = w + 8 * n;          // [0,16)
                floatx4 acc[4] = {};
                #pragma unroll
                for (int ks = 0; ks < 8; ++ks) {
                    const int k0 = ks * 32 + kq * 8;
                    bf16x8 bf = *(const bf16x8*)&WallT[(head * 256 + ct * 16 + ml) * 256 + k0];
                    #pragma unroll
                    for (int mt = 0; mt < 4; ++mt) {
                        bf16x8 a = *(const bf16x8*)&sh.hd.Xs[(mt * 16 + ml) * SK + k0];
                        acc[mt] = __builtin_amdgcn_mfma_f32_16x16x32_bf16(a, bf, acc[mt], 0, 0, 0);
                    }
                }
                const int col = ct * 16 + ml;      // [0,256)
                const float bias = biasF[head * 256 + col];   // bs1 | bc1
                #pragma unroll
                for (int mt = 0; mt < 4; ++mt)
                    #pragma unroll
                    for (int r = 0; r < 4; ++r)
                        sh.hd.Hb[(mt * 16 + r0 + r) * SK + col] = f2bf(lrelu(acc[mt][r] + bias));
            }
            __syncthreads();   // Hb complete

            // ---- layer 2: waves 0..3 own M-tile w ----
            if (w < 4) {
                const int nct = (head == 0) ? 3 : 1;   // block-uniform
                const int c0  = (head == 0) ? 0 : 48;
                floatx4 acc2[3] = {};
                #pragma unroll
                for (int ks = 0; ks < 8; ++ks) {
                    const int k0 = ks * 32 + kq * 8;
                    bf16x8 a = *(const bf16x8*)&sh.hd.Hb[(w * 16 + ml) * SK + k0];
                    #pragma unroll
                    for (int j = 0; j < 3; ++j) {
                        if (j < nct) {
                            bf16x8 bf = *(const bf16x8*)&W2T[(c0 + j * 16 + ml) * 256 + k0];
                            acc2[j] = __builtin_amdgcn_mfma_f32_16x16x32_bf16(a, bf, acc2[j], 0, 0, 0);
                        }
                    }
                }
                #pragma unroll
                for (int j = 0; j < 3; ++j) {
                    if (j < nct) {
                        const int col = j * 16 + ml;
                        const int lim = (head == 0) ? 40 : 5;
                        if (col < lim) {
                            const float bias = biasF[(head == 0 ? 768 : 808) + col];
                            #pragma unroll
                            for (int r = 0; r < 4; ++r) {
                                const int row = bm0 + w * 16 + r0 + r;
                                const int o = (head == 0) ? row * 40 + col
                                                          : 409600 + row * 5 + col;
                                const float v = acc2[j][r] + bias;
                                if (isF32) ((float*)outv)[o] = v;
                                else ((__hip_bfloat16*)outv)[o] = __float2bfloat16(v);
                            }
                        }
                    }
                }
            }
            __syncthreads();   // L2 reads done before head=1 overwrites Hb
        }
    }
}

// ---------------------------------------------------------------------------
extern "C" void kernel_launch(void* const* d_in, const int* in_sizes, int n_in,
                              void* d_out, int out_size, void* d_ws, size_t ws_size,
                              hipStream_t stream)
{
    const void* yhat = d_in[0];
    const void* Ws1  = d_in[1];
    const void* bs1  = d_in[2];
    const void* Ws2  = d_in[3];
    const void* bs2  = d_in[4];
    const void* Wc1  = d_in[5];
    const void* bc1  = d_in[6];
    const void* Wc2  = d_in[7];
    const void* bc2  = d_in[8];
    const void* Wb1  = d_in[9];
    const void* bb1  = d_in[10];
    const void* Wb2  = d_in[11];
    const void* bb2  = d_in[12];

    // workspace: 565248 bytes total (verified R0 layout)
    char* wsb = (char*)d_ws;
    float* biasF = (float*)(wsb + 4096);     // 1024 floats
    u16*   W2T   = (u16*)(wsb + 8192);       // 64*256 bf16  = 32768 B
    u16*   WallT = (u16*)(wsb + 40960);      // 1024*256 bf16 = 524288 B

    pack_kernel<<<132, 256, 0, stream>>>(yhat, Ws1, Wc1, Wb1, Ws2, Wc2,
                                         bs1, bc1, bb1, bs2, bc2, bb2,
                                         WallT, W2T, biasF);
    fused_kernel<<<416, 512, 0, stream>>>(yhat, WallT, W2T, Wb2, biasF, d_out);
}